// Round 2
// baseline (1217.917 us; speedup 1.0000x reference)
//
#include <hip/hip_runtime.h>

typedef unsigned short u16;
typedef unsigned int   u32;
typedef __bf16 bf16_t;
typedef bf16_t bf16x8 __attribute__((ext_vector_type(8)));
typedef float  f32x4  __attribute__((ext_vector_type(4)));

#define DEV static __device__ __forceinline__

// ---- constants ----
// B=4096, L=17, D_MODEL=512, D_INNER=1024, D_STATE=4, DT_RANK=32
// M = B*L = 69632 = 544 * 128
__constant__ int c_HOP[17] = {0,1,4,7,2,5,8,3,6,9,11,14,10,12,15,13,16};
__constant__ int c_BPE[17] = {0,1,2,0,1,2,0,1,2,0,3,4,0,3,4,3,4};
// GRAPH is HOP^-1, so out row for ssm row (b,gl) is b*17 + HOP[gl].

DEV u16 f2bf(float f){
  u32 x = __builtin_bit_cast(u32, f);
  x += 0x7fffu + ((x >> 16) & 1u);        // RNE (no NaN inputs here)
  return (u16)(x >> 16);
}
DEV float bf2f(u32 u){ return __builtin_bit_cast(float, u << 16); }
DEV float silu_f(float v){ return v / (1.f + __expf(-v)); }

DEV void gll16(const void* g, void* l){
  // async global->LDS, 16B per lane; LDS dest is wave-uniform base + lane*16
  __builtin_amdgcn_global_load_lds((__attribute__((address_space(1))) void*)g,
                                   (__attribute__((address_space(3))) void*)l,
                                   16, 0, 0);
}

// ---------------- weight f32 -> bf16 conversion ----------------
__global__ __launch_bounds__(256) void cvt4(
    const float* __restrict__ s0, u16* __restrict__ d0, int n0,
    const float* __restrict__ s1, u16* __restrict__ d1, int n1,
    const float* __restrict__ s2, u16* __restrict__ d2, int n2,
    const float* __restrict__ s3, u16* __restrict__ d3, int n3)
{
  int t = blockIdx.x * 256 + threadIdx.x;
  if (t < n0){ d0[t] = f2bf(s0[t]); return; }
  t -= n0; if (t < n1){ d1[t] = f2bf(s1[t]); return; }
  t -= n1; if (t < n2){ d2[t] = f2bf(s2[t]); return; }
  t -= n2; if (t < n3){ d3[t] = f2bf(s3[t]); }
}

// ---------------- gather + bpe + layernorm -> u (bf16) ----------------
__global__ __launch_bounds__(256) void ln_gather(
    const float* __restrict__ x, const float* __restrict__ bpe,
    const float* __restrict__ lnw, const float* __restrict__ lnb,
    u16* __restrict__ u)
{
  int tok = blockIdx.x;            // b*17 + l
  int b = tok / 17;
  int l = tok - b * 17;
  const float* xr = x   + ((size_t)b * 17 + c_HOP[l]) * 512;
  const float* br = bpe + (size_t)c_BPE[l] * 512;
  int tid = threadIdx.x;
  int d0 = tid * 2;
  float2 xv = *(const float2*)(xr + d0);
  float2 bv = *(const float2*)(br + d0);
  float v0 = xv.x + bv.x, v1 = xv.y + bv.y;

  __shared__ float red[8];
  float s = v0 + v1;
  #pragma unroll
  for (int o = 32; o; o >>= 1) s += __shfl_xor(s, o);
  if ((tid & 63) == 0) red[tid >> 6] = s;
  __syncthreads();
  float mu = (red[0] + red[1] + red[2] + red[3]) * (1.f / 512.f);
  float a0 = v0 - mu, a1 = v1 - mu;
  float q = a0 * a0 + a1 * a1;
  #pragma unroll
  for (int o = 32; o; o >>= 1) q += __shfl_xor(q, o);
  if ((tid & 63) == 0) red[4 + (tid >> 6)] = q;
  __syncthreads();
  float var = (red[4] + red[5] + red[6] + red[7]) * (1.f / 512.f);
  float rs = rsqrtf(var + 1e-5f);

  u16 o0 = f2bf(a0 * rs * lnw[d0]     + lnb[d0]);
  u16 o1 = f2bf(a1 * rs * lnw[d0 + 1] + lnb[d0 + 1]);
  u32 pack = (u32)o0 | ((u32)o1 << 16);
  *(u32*)(u + (size_t)tok * 512 + d0) = pack;
}

// ---------------- MFMA GEMM: C = A(MxK) * W(nW x K)^T ----------------
// 128x128 tile, BK=32, 4 waves (2x2), each wave 64x64 via 4x4 mfma 16x16x32.
// Grid: nt fastest (A-panel reuse in L2), bijective XCD swizzle on top.
// LDS chunk-XOR swizzle: physical chunk p = logical chunk c ^ ((row>>1)&3).
enum { EPI_SPLIT = 0, EPI_OUT = 1 };

template<int EPI>
__global__ __launch_bounds__(256) void gemm_bt(
    const u16* __restrict__ A, int lda,
    const u16* __restrict__ W, int K, int MT,
    u16* __restrict__ ob0, u16* __restrict__ ob1,
    const float* __restrict__ p0, const float* __restrict__ p1,
    const float* __restrict__ xres, float* __restrict__ fout)
{
  __shared__ u16 sA[128 * 32];
  __shared__ u16 sW[128 * 32];
  // bijective XCD swizzle (gridDim.x % 8 == 0 for all launches here):
  // XCD x gets a contiguous wg-range -> contiguous M-range, W stays L2-hot.
  int nwg = gridDim.x;
  int cpx = nwg >> 3;
  int wg = (blockIdx.x & 7) * cpx + (blockIdx.x >> 3);
  int NT = nwg / MT;
  int nt = wg % NT, mt = wg / NT;      // nt fastest: A-panel reused by consecutive blocks
  int brow = mt * 128, bcol = nt * 128;
  int tid = threadIdx.x, lane = tid & 63, wid = tid >> 6;
  int wm = wid >> 1, wn = wid & 1;

  f32x4 acc[4][4] = {};

  int srow = tid >> 2;   // 0..63
  int sch  = tid & 3;    // physical chunk

  for (int kt = 0; kt < K; kt += 32) {
    #pragma unroll
    for (int i = 0; i < 2; i++) {
      int r = i * 64 + srow;
      int c = sch ^ ((r >> 1) & 3);
      gll16(A + (size_t)(brow + r) * lda + kt + c * 8,
            (char*)sA + tid * 16 + i * 4096);
    }
    #pragma unroll
    for (int i = 0; i < 2; i++) {
      int r = i * 64 + srow;
      int c = sch ^ ((r >> 1) & 3);
      gll16(W + (size_t)(bcol + r) * K + kt + c * 8,
            (char*)sW + tid * 16 + i * 4096);
    }
    __syncthreads();

    bf16x8 av[4], bv[4];
    #pragma unroll
    for (int mi = 0; mi < 4; mi++) {
      int r = wm * 64 + mi * 16 + (lane & 15);
      int c = (lane >> 4) ^ ((r >> 1) & 3);
      av[mi] = *(const bf16x8*)((const char*)sA + r * 64 + c * 16);
    }
    #pragma unroll
    for (int ni = 0; ni < 4; ni++) {
      int r = wn * 64 + ni * 16 + (lane & 15);
      int c = (lane >> 4) ^ ((r >> 1) & 3);
      bv[ni] = *(const bf16x8*)((const char*)sW + r * 64 + c * 16);
    }
    #pragma unroll
    for (int mi = 0; mi < 4; mi++)
      #pragma unroll
      for (int ni = 0; ni < 4; ni++)
        acc[mi][ni] = __builtin_amdgcn_mfma_f32_16x16x32_bf16(
            av[mi], bv[ni], acc[mi][ni], 0, 0, 0);
    __syncthreads();
  }

  // epilogue: D[row=(lane>>4)*4+rr][col=lane&15] per 16x16 fragment
  int r4 = (lane >> 4) * 4;
  int cl = lane & 15;
  #pragma unroll
  for (int mi = 0; mi < 4; mi++) {
    int rowb = brow + wm * 64 + mi * 16 + r4;
    #pragma unroll
    for (int ni = 0; ni < 4; ni++) {
      int col = bcol + wn * 64 + ni * 16 + cl;
      if constexpr (EPI == EPI_SPLIT) {
        // cols [0,1024): xm = silu(v*conv_w+conv_b); [1024,2048): zs = silu(v)
        // branch is uniform per fragment (bcol multiple of 128).
        bool isx = (col < 1024);
        float cw = isx ? p0[col] : 1.f;
        float cb = isx ? p1[col] : 0.f;
        float rv[4];
        #pragma unroll
        for (int rr = 0; rr < 4; rr++)
          rv[rr] = silu_f(acc[mi][ni][rr] * cw + cb);
        // pair-pack with neighbor lane (cols c, c+1) -> one u32 store
        #pragma unroll
        for (int rr = 0; rr < 4; rr++) {
          float ov = __shfl_xor(rv[rr], 1);
          if (!(lane & 1)) {
            u32 pk = (u32)f2bf(rv[rr]) | ((u32)f2bf(ov) << 16);
            size_t rowoff = (size_t)(rowb + rr) * 1024;
            if (isx) *(u32*)(ob0 + rowoff + col) = pk;
            else     *(u32*)(ob1 + rowoff + (col - 1024)) = pk;
          }
        }
      } else {  // EPI_OUT: residual add + GRAPH^-1(=HOP) scatter
        #pragma unroll
        for (int rr = 0; rr < 4; rr++) {
          int row = rowb + rr;
          u32 rw = (u32)row;
          u32 b = rw / 17u;
          int gl = (int)(rw - b * 17u);
          size_t oi = ((size_t)b * 17 + c_HOP[gl]) * 512 + col;
          fout[oi] = xres[oi] + acc[mi][ni][rr];
        }
      }
    }
  }
}

// ---------------- fused x_proj + dt_proj + selective scan ----------------
// One block (256 threads, 4 waves) per batch element b.
// Phase 1: x_dbl[17][40] = xm[b] @ w_xp^T  (MFMA, K split across waves)
// Phase 2: dt[17][1024] = softplus(x_dbl[:, :32] @ w_dt^T + b_dt)  (MFMA)
// Phase 3: per-(e) scan over 17 tokens; B/C fp32 from LDS; y written bf16.
__global__ __launch_bounds__(256) void mamba_mid(
    const u16* __restrict__ xm, const u16* __restrict__ zs,
    const u16* __restrict__ wxp, const u16* __restrict__ wdt,
    const float* __restrict__ bdt, const float* __restrict__ A_log,
    const float* __restrict__ Dp, u16* __restrict__ y)
{
  __shared__ float part[4][17][52];   // per-wave K-partials (padded stride)
  __shared__ float xdbl_s[17][52];    // x_dbl fp32 (cols 0..39 valid)
  __shared__ u16 dt_s[17][1032];      // dt bf16 (padded stride vs bank conflicts)

  int b = blockIdx.x;
  int tid = threadIdx.x, lane = tid & 63, wid = tid >> 6;
  int l15 = lane & 15, lhi = lane >> 4;
  const size_t base = (size_t)b * 17 * 1024;

  // ---- phase 1: x_proj (M=17 pad 32, N=40 pad 48, K=1024 split 4 ways) ----
  {
    f32x4 acc1[2][3] = {};
    int k0 = wid * 256;
    for (int ks = 0; ks < 8; ks++) {
      int kk = k0 + ks * 32 + lhi * 8;
      bf16x8 a0 = *(const bf16x8*)(xm + base + (size_t)l15 * 1024 + kk);
      bf16x8 a1 = *(const bf16x8*)(xm + base + (size_t)16  * 1024 + kk); // row 16 (rows 17..31 clamped)
      #pragma unroll
      for (int nf = 0; nf < 3; nf++) {
        int f = nf * 16 + l15; f = (f < 40) ? f : 39;
        bf16x8 bv = *(const bf16x8*)(wxp + (size_t)f * 1024 + kk);
        acc1[0][nf] = __builtin_amdgcn_mfma_f32_16x16x32_bf16(a0, bv, acc1[0][nf], 0,0,0);
        acc1[1][nf] = __builtin_amdgcn_mfma_f32_16x16x32_bf16(a1, bv, acc1[1][nf], 0,0,0);
      }
    }
    #pragma unroll
    for (int mi = 0; mi < 2; mi++)
      #pragma unroll
      for (int nf = 0; nf < 3; nf++)
        #pragma unroll
        for (int rr = 0; rr < 4; rr++) {
          int row = mi * 16 + lhi * 4 + rr;
          if (row < 17) part[wid][row][nf * 16 + l15] = acc1[mi][nf][rr];
        }
  }
  __syncthreads();
  for (int i = tid; i < 17 * 48; i += 256) {
    int t = i / 48, c = i - t * 48;
    xdbl_s[t][c] = part[0][t][c] + part[1][t][c] + part[2][t][c] + part[3][t][c];
  }
  __syncthreads();

  // ---- phase 2: dt (M=17 pad 32, N=1024 split 4 ways, K=32) ----
  {
    bf16x8 a2_0, a2_1;
    int kk2 = lhi * 8;
    #pragma unroll
    for (int j = 0; j < 8; j++) {
      a2_0[j] = (bf16_t)xdbl_s[l15][kk2 + j];
      a2_1[j] = (bf16_t)xdbl_s[16][kk2 + j];
    }
    #pragma unroll
    for (int half = 0; half < 2; half++) {
      f32x4 acc2[2][8] = {};
      #pragma unroll
      for (int nf = 0; nf < 8; nf++) {
        int e = (wid * 16 + half * 8 + nf) * 16 + l15;
        bf16x8 bv = *(const bf16x8*)(wdt + (size_t)e * 32 + kk2);
        acc2[0][nf] = __builtin_amdgcn_mfma_f32_16x16x32_bf16(a2_0, bv, acc2[0][nf], 0,0,0);
        acc2[1][nf] = __builtin_amdgcn_mfma_f32_16x16x32_bf16(a2_1, bv, acc2[1][nf], 0,0,0);
      }
      #pragma unroll
      for (int nf = 0; nf < 8; nf++) {
        int e = (wid * 16 + half * 8 + nf) * 16 + l15;
        float bb = bdt[e];
        #pragma unroll
        for (int mi = 0; mi < 2; mi++)
          #pragma unroll
          for (int rr = 0; rr < 4; rr++) {
            int t = mi * 16 + lhi * 4 + rr;
            if (t < 17) {
              float s = acc2[mi][nf][rr] + bb;
              float d = (s > 20.f) ? s : log1pf(__expf(s));
              dt_s[t][e] = f2bf(d);
            }
          }
      }
    }
  }
  __syncthreads();

  // ---- phase 3: scan (thread -> channel e, 4 channels each) ----
  const u16* xmb = xm + base;
  const u16* zsb = zs + base;
  u16* yb = y + base;
  for (int c = 0; c < 4; c++) {
    int e = c * 256 + tid;
    float4 al = *(const float4*)(A_log + (size_t)e * 4);
    float Av0 = -__expf(al.x), Av1 = -__expf(al.y);
    float Av2 = -__expf(al.z), Av3 = -__expf(al.w);
    float Dv = Dp[e];
    float h0 = 0.f, h1 = 0.f, h2 = 0.f, h3 = 0.f;
    #pragma unroll
    for (int t = 0; t < 17; t++) {
      int off = t * 1024 + e;
      float dtv = bf2f(dt_s[t][e]);
      float xv = bf2f(xmb[off]);
      float zv = bf2f(zsb[off]);
      float B0 = xdbl_s[t][32], B1 = xdbl_s[t][33];
      float B2 = xdbl_s[t][34], B3 = xdbl_s[t][35];
      float C0 = xdbl_s[t][36], C1 = xdbl_s[t][37];
      float C2 = xdbl_s[t][38], C3 = xdbl_s[t][39];
      float dx = dtv * xv;
      h0 = __expf(dtv * Av0) * h0 + dx * B0;
      h1 = __expf(dtv * Av1) * h1 + dx * B1;
      h2 = __expf(dtv * Av2) * h2 + dx * B2;
      h3 = __expf(dtv * Av3) * h3 + dx * B3;
      float yv = h0 * C0 + h1 * C1 + h2 * C2 + h3 * C3;
      yb[off] = f2bf((yv + xv * Dv) * zv);
    }
  }
}

// ---------------- launch ----------------
extern "C" void kernel_launch(void* const* d_in, const int* in_sizes, int n_in,
                              void* d_out, int out_size, void* d_ws, size_t ws_size,
                              hipStream_t stream) {
  const float* x     = (const float*)d_in[0];
  const float* bpe   = (const float*)d_in[1];
  const float* lnw   = (const float*)d_in[2];
  const float* lnb   = (const float*)d_in[3];
  const float* w_in  = (const float*)d_in[4];   // (2048, 512)
  const float* convw = (const float*)d_in[5];
  const float* convb = (const float*)d_in[6];
  const float* w_xp  = (const float*)d_in[7];   // (40, 1024)
  const float* w_dt  = (const float*)d_in[8];   // (1024, 32)
  const float* b_dt  = (const float*)d_in[9];
  const float* A_log = (const float*)d_in[10];  // (1024, 4)
  const float* Dp    = (const float*)d_in[11];
  const float* w_out = (const float*)d_in[12];  // (512, 1024)
  float* out = (float*)d_out;

  // workspace layout (u16 elements)
  u16* ws = (u16*)d_ws;
  u16* wb_in  = ws;                       // 2048*512   = 1048576
  u16* wb_out = wb_in  + 1048576;         // 512*1024   = 524288
  u16* wb_xp  = wb_out + 524288;          // 40*1024    = 40960
  u16* wb_dt  = wb_xp  + 40960;           // 1024*32    = 32768
  u16* xm     = wb_dt  + 32768;           // 69632*1024 = 71303168
  u16* zs     = xm     + 71303168;        // 69632*1024
  u16* yv     = zs     + 71303168;        // 69632*1024 (y)
  u16* u      = yv;                       // 69632*512 — u dead before y is written

  const int MT = 544;   // 69632 / 128

  cvt4<<<6432, 256, 0, stream>>>(w_in, wb_in, 1048576, w_out, wb_out, 524288,
                                 w_xp, wb_xp, 40960, w_dt, wb_dt, 32768);

  ln_gather<<<69632, 256, 0, stream>>>(x, bpe, lnw, lnb, u);

  // xz = u @ in_proj^T  -> xm = silu(conv(xm)), zs = silu(z)
  gemm_bt<EPI_SPLIT><<<MT * 16, 256, 0, stream>>>(
      u, 512, wb_in, 512, MT, xm, zs, convw, convb, nullptr, nullptr);

  // fused x_proj + dt + scan -> y
  mamba_mid<<<4096, 256, 0, stream>>>(xm, zs, wb_xp, wb_dt, b_dt, A_log, Dp, yv);

  // out = x + (y @ out_proj^T) scattered through HOP
  gemm_bt<EPI_OUT><<<MT * 4, 256, 0, stream>>>(
      yv, 1024, wb_out, 1024, MT, nullptr, nullptr, nullptr, nullptr, x, out);
}

// Round 3
// 913.574 us; speedup vs baseline: 1.3331x; 1.3331x over previous
//
#include <hip/hip_runtime.h>

typedef unsigned short u16;
typedef unsigned int   u32;
typedef __bf16 bf16_t;
typedef bf16_t bf16x8 __attribute__((ext_vector_type(8)));
typedef float  f32x4  __attribute__((ext_vector_type(4)));

#define DEV static __device__ __forceinline__

// ---- constants ----
// B=4096, L=17, D_MODEL=512, D_INNER=1024, D_STATE=4, DT_RANK=32
// M = B*L = 69632 = 544 * 128
__constant__ int c_HOP[17] = {0,1,4,7,2,5,8,3,6,9,11,14,10,12,15,13,16};
__constant__ int c_BPE[17] = {0,1,2,0,1,2,0,1,2,0,3,4,0,3,4,3,4};
// GRAPH is HOP^-1, so out row for ssm row (b,gl) is b*17 + HOP[gl].

DEV u16 f2bf(float f){
  u32 x = __builtin_bit_cast(u32, f);
  x += 0x7fffu + ((x >> 16) & 1u);        // RNE (no NaN inputs here)
  return (u16)(x >> 16);
}
DEV float bf2f(u32 u){ return __builtin_bit_cast(float, u << 16); }
DEV float silu_f(float v){ return v / (1.f + __expf(-v)); }
DEV float softplus_f(float s){ return (s > 20.f) ? s : log1pf(__expf(s)); }

DEV void gll16(const void* g, void* l){
  __builtin_amdgcn_global_load_lds((__attribute__((address_space(1))) void*)g,
                                   (__attribute__((address_space(3))) void*)l,
                                   16, 0, 0);
}

// ---------------- weight f32 -> bf16 conversion ----------------
__global__ __launch_bounds__(256) void cvt4(
    const float* __restrict__ s0, u16* __restrict__ d0, int n0,
    const float* __restrict__ s1, u16* __restrict__ d1, int n1,
    const float* __restrict__ s2, u16* __restrict__ d2, int n2,
    const float* __restrict__ s3, u16* __restrict__ d3, int n3)
{
  int t = blockIdx.x * 256 + threadIdx.x;
  if (t < n0){ d0[t] = f2bf(s0[t]); return; }
  t -= n0; if (t < n1){ d1[t] = f2bf(s1[t]); return; }
  t -= n1; if (t < n2){ d2[t] = f2bf(s2[t]); return; }
  t -= n2; if (t < n3){ d3[t] = f2bf(s3[t]); }
}

// ---------------- gather + bpe + layernorm -> u (bf16) ----------------
__global__ __launch_bounds__(256) void ln_gather(
    const float* __restrict__ x, const float* __restrict__ bpe,
    const float* __restrict__ lnw, const float* __restrict__ lnb,
    u16* __restrict__ u)
{
  int tok = blockIdx.x;            // b*17 + l
  int b = tok / 17;
  int l = tok - b * 17;
  const float* xr = x   + ((size_t)b * 17 + c_HOP[l]) * 512;
  const float* br = bpe + (size_t)c_BPE[l] * 512;
  int tid = threadIdx.x;
  int d0 = tid * 2;
  float2 xv = *(const float2*)(xr + d0);
  float2 bv = *(const float2*)(br + d0);
  float v0 = xv.x + bv.x, v1 = xv.y + bv.y;

  __shared__ float red[8];
  float s = v0 + v1;
  #pragma unroll
  for (int o = 32; o; o >>= 1) s += __shfl_xor(s, o);
  if ((tid & 63) == 0) red[tid >> 6] = s;
  __syncthreads();
  float mu = (red[0] + red[1] + red[2] + red[3]) * (1.f / 512.f);
  float a0 = v0 - mu, a1 = v1 - mu;
  float q = a0 * a0 + a1 * a1;
  #pragma unroll
  for (int o = 32; o; o >>= 1) q += __shfl_xor(q, o);
  if ((tid & 63) == 0) red[4 + (tid >> 6)] = q;
  __syncthreads();
  float var = (red[4] + red[5] + red[6] + red[7]) * (1.f / 512.f);
  float rs = rsqrtf(var + 1e-5f);

  u16 o0 = f2bf(a0 * rs * lnw[d0]     + lnb[d0]);
  u16 o1 = f2bf(a1 * rs * lnw[d0 + 1] + lnb[d0 + 1]);
  u32 pack = (u32)o0 | ((u32)o1 << 16);
  *(u32*)(u + (size_t)tok * 512 + d0) = pack;
}

// ---------------- MFMA GEMM: C = A(MxK) * W(nW x K)^T ----------------
// 128x128 tile, BK=32, 4 waves (2x2), each wave 64x64 via 4x4 mfma 16x16x32.
// Grid: nt fastest (A-panel reuse in L2), bijective XCD swizzle on top.
enum { EPI_SPLIT = 0, EPI_XDBL = 1, EPI_OUT = 2 };

template<int EPI>
__global__ __launch_bounds__(256) void gemm_bt(
    const u16* __restrict__ A, int lda,
    const u16* __restrict__ W, int K, int MT,
    u16* __restrict__ ob0, u16* __restrict__ ob1,
    const float* __restrict__ p0, const float* __restrict__ p1,
    const float* __restrict__ xres, float* __restrict__ fout)
{
  __shared__ u16 sA[128 * 32];
  __shared__ u16 sW[128 * 32];
  int nwg = gridDim.x;
  int cpx = nwg >> 3;
  int wg = (blockIdx.x & 7) * cpx + (blockIdx.x >> 3);
  int NT = nwg / MT;
  int nt = wg % NT, mt = wg / NT;
  int brow = mt * 128, bcol = nt * 128;
  int tid = threadIdx.x, lane = tid & 63, wid = tid >> 6;
  int wm = wid >> 1, wn = wid & 1;

  f32x4 acc[4][4] = {};

  int srow = tid >> 2;
  int sch  = tid & 3;

  for (int kt = 0; kt < K; kt += 32) {
    #pragma unroll
    for (int i = 0; i < 2; i++) {
      int r = i * 64 + srow;
      int c = sch ^ ((r >> 1) & 3);
      gll16(A + (size_t)(brow + r) * lda + kt + c * 8,
            (char*)sA + tid * 16 + i * 4096);
    }
    #pragma unroll
    for (int i = 0; i < 2; i++) {
      int r = i * 64 + srow;
      int c = sch ^ ((r >> 1) & 3);
      gll16(W + (size_t)(bcol + r) * K + kt + c * 8,
            (char*)sW + tid * 16 + i * 4096);
    }
    __syncthreads();

    bf16x8 av[4], bv[4];
    #pragma unroll
    for (int mi = 0; mi < 4; mi++) {
      int r = wm * 64 + mi * 16 + (lane & 15);
      int c = (lane >> 4) ^ ((r >> 1) & 3);
      av[mi] = *(const bf16x8*)((const char*)sA + r * 64 + c * 16);
    }
    #pragma unroll
    for (int ni = 0; ni < 4; ni++) {
      int r = wn * 64 + ni * 16 + (lane & 15);
      int c = (lane >> 4) ^ ((r >> 1) & 3);
      bv[ni] = *(const bf16x8*)((const char*)sW + r * 64 + c * 16);
    }
    #pragma unroll
    for (int mi = 0; mi < 4; mi++)
      #pragma unroll
      for (int ni = 0; ni < 4; ni++)
        acc[mi][ni] = __builtin_amdgcn_mfma_f32_16x16x32_bf16(
            av[mi], bv[ni], acc[mi][ni], 0, 0, 0);
    __syncthreads();
  }

  int r4 = (lane >> 4) * 4;
  int cl = lane & 15;
  #pragma unroll
  for (int mi = 0; mi < 4; mi++) {
    int rowb = brow + wm * 64 + mi * 16 + r4;
    #pragma unroll
    for (int ni = 0; ni < 4; ni++) {
      int col = bcol + wn * 64 + ni * 16 + cl;
      if constexpr (EPI == EPI_SPLIT) {
        bool isx = (col < 1024);
        float cw = isx ? p0[col] : 1.f;
        float cb = isx ? p1[col] : 0.f;
        float rv[4];
        #pragma unroll
        for (int rr = 0; rr < 4; rr++)
          rv[rr] = silu_f(acc[mi][ni][rr] * cw + cb);
        #pragma unroll
        for (int rr = 0; rr < 4; rr++) {
          float ov = __shfl_xor(rv[rr], 1);
          if (!(lane & 1)) {
            u32 pk = (u32)f2bf(rv[rr]) | ((u32)f2bf(ov) << 16);
            size_t rowoff = (size_t)(rowb + rr) * 1024;
            if (isx) *(u32*)(ob0 + rowoff + col) = pk;
            else     *(u32*)(ob1 + rowoff + (col - 1024)) = pk;
          }
        }
      } else if constexpr (EPI == EPI_XDBL) {
        if (col < 40) {
          #pragma unroll
          for (int rr = 0; rr < 4; rr++)
            ob0[(size_t)(rowb + rr) * 40 + col] = f2bf(acc[mi][ni][rr]);
        }
      } else {  // EPI_OUT
        #pragma unroll
        for (int rr = 0; rr < 4; rr++) {
          int row = rowb + rr;
          u32 rw = (u32)row;
          u32 b = rw / 17u;
          int gl = (int)(rw - b * 17u);
          size_t oi = ((size_t)b * 17 + c_HOP[gl]) * 512 + col;
          fout[oi] = xres[oi] + acc[mi][ni][rr];
        }
      }
    }
  }
}

// ---------------- fused dt_proj + selective scan ----------------
// Grid: 16384 blocks = 4096 batches x 4 e-strips of 256. Thread <-> (b, e).
__global__ __launch_bounds__(256) void scan2(
    const u16* __restrict__ xm, const u16* __restrict__ zs,
    const u16* __restrict__ xdbl, const u16* __restrict__ wdt,
    const float* __restrict__ bdt, const float* __restrict__ A_log,
    const float* __restrict__ Dp, u16* __restrict__ y)
{
  __shared__ u16 xs[17 * 40];          // x_dbl[b] raw bf16 (1360 B)
  __shared__ u16 dt_s[17][264];        // softplus(dt) bf16; 528B stride

  int b = blockIdx.x >> 2;
  int er0 = (blockIdx.x & 3) * 256;
  int tid = threadIdx.x, lane = tid & 63, wid = tid >> 6;
  int l15 = lane & 15, lhi = lane >> 4;
  const size_t base = (size_t)b * 17 * 1024;

  {
    const u32* src = (const u32*)(xdbl + (size_t)b * 680);
    for (int i = tid; i < 340; i += 256) ((u32*)xs)[i] = src[i];
  }
  __syncthreads();

  // dt = softplus(x_dbl[:, :32] @ wdt^T + bdt) — M=17(pad32), K=32,
  // wave covers 64 e-columns (4 N-frags), 8 MFMA total.
  {
    bf16x8 a0 = *(const bf16x8*)(xs + l15 * 40 + lhi * 8);  // rows t=0..15
    bf16x8 a1 = *(const bf16x8*)(xs + 16 * 40 + lhi * 8);   // row t=16
    #pragma unroll
    for (int nf = 0; nf < 4; nf++) {
      int colc = wid * 64 + nf * 16 + l15;     // bijective over 0..255
      int e = er0 + colc;
      bf16x8 bv = *(const bf16x8*)(wdt + (size_t)e * 32 + lhi * 8);
      f32x4 c0 = {}, c1 = {};
      c0 = __builtin_amdgcn_mfma_f32_16x16x32_bf16(a0, bv, c0, 0, 0, 0);
      c1 = __builtin_amdgcn_mfma_f32_16x16x32_bf16(a1, bv, c1, 0, 0, 0);
      float bb = bdt[e];
      #pragma unroll
      for (int rr = 0; rr < 4; rr++) {
        int t = lhi * 4 + rr;
        if (t < 17) dt_s[t][colc] = f2bf(softplus_f(c0[rr] + bb));
      }
      if (lhi == 0) dt_s[16][colc] = f2bf(softplus_f(c1[0] + bb));
    }
  }
  __syncthreads();

  // scan: thread owns channel e = er0 + tid
  {
    int e = er0 + tid;
    float4 al = *(const float4*)(A_log + (size_t)e * 4);
    float Av0 = -__expf(al.x), Av1 = -__expf(al.y);
    float Av2 = -__expf(al.z), Av3 = -__expf(al.w);
    float Dv = Dp[e];
    const u16* xmb = xm + base + e;
    const u16* zsb = zs + base + e;
    u16* yb = y + base + e;
    float h0 = 0.f, h1 = 0.f, h2 = 0.f, h3 = 0.f;
    #pragma unroll
    for (int t = 0; t < 17; t++) {
      float dtv = bf2f(dt_s[t][tid]);
      float xv = bf2f(xmb[t * 1024]);
      float zv = bf2f(zsb[t * 1024]);
      uint4 raw = *(const uint4*)(xs + t * 40 + 32);   // B,C bf16 broadcast
      float B0 = bf2f(raw.x & 0xffffu), B1 = bf2f(raw.x >> 16);
      float B2 = bf2f(raw.y & 0xffffu), B3 = bf2f(raw.y >> 16);
      float C0 = bf2f(raw.z & 0xffffu), C1 = bf2f(raw.z >> 16);
      float C2 = bf2f(raw.w & 0xffffu), C3 = bf2f(raw.w >> 16);
      float dx = dtv * xv;
      h0 = __expf(dtv * Av0) * h0 + dx * B0;
      h1 = __expf(dtv * Av1) * h1 + dx * B1;
      h2 = __expf(dtv * Av2) * h2 + dx * B2;
      h3 = __expf(dtv * Av3) * h3 + dx * B3;
      float yv = h0 * C0 + h1 * C1 + h2 * C2 + h3 * C3;
      yb[t * 1024] = f2bf((yv + xv * Dv) * zv);
    }
  }
}

// ---------------- launch ----------------
extern "C" void kernel_launch(void* const* d_in, const int* in_sizes, int n_in,
                              void* d_out, int out_size, void* d_ws, size_t ws_size,
                              hipStream_t stream) {
  const float* x     = (const float*)d_in[0];
  const float* bpe   = (const float*)d_in[1];
  const float* lnw   = (const float*)d_in[2];
  const float* lnb   = (const float*)d_in[3];
  const float* w_in  = (const float*)d_in[4];   // (2048, 512)
  const float* convw = (const float*)d_in[5];
  const float* convb = (const float*)d_in[6];
  const float* w_xp  = (const float*)d_in[7];   // (40, 1024)
  const float* w_dt  = (const float*)d_in[8];   // (1024, 32)
  const float* b_dt  = (const float*)d_in[9];
  const float* A_log = (const float*)d_in[10];  // (1024, 4)
  const float* Dp    = (const float*)d_in[11];
  const float* w_out = (const float*)d_in[12];  // (512, 1024)
  float* out = (float*)d_out;

  // workspace layout (u16 elements) — total 218,341,376 u16 = ~437 MB
  u16* ws = (u16*)d_ws;
  u16* wb_in  = ws;                       // 1048576
  u16* wb_out = wb_in  + 1048576;         // 524288
  u16* wb_xp  = wb_out + 524288;          // 40960
  u16* wb_dt  = wb_xp  + 40960;           // 32768
  u16* xm     = wb_dt  + 32768;           // 71303168
  u16* zs     = xm     + 71303168;        // 71303168
  u16* xdbl   = zs     + 71303168;        // 2785280
  u16* yv     = xdbl   + 2785280;         // 71303168
  u16* u      = yv;                       // 69632*512 — dead before yv written

  const int MT = 544;   // 69632 / 128

  cvt4<<<6432, 256, 0, stream>>>(w_in, wb_in, 1048576, w_out, wb_out, 524288,
                                 w_xp, wb_xp, 40960, w_dt, wb_dt, 32768);

  ln_gather<<<69632, 256, 0, stream>>>(x, bpe, lnw, lnb, u);

  gemm_bt<EPI_SPLIT><<<MT * 16, 256, 0, stream>>>(
      u, 512, wb_in, 512, MT, xm, zs, convw, convb, nullptr, nullptr);

  gemm_bt<EPI_XDBL><<<MT * 1, 256, 0, stream>>>(
      xm, 1024, wb_xp, 1024, MT, xdbl, nullptr, nullptr, nullptr, nullptr, nullptr);

  scan2<<<16384, 256, 0, stream>>>(xm, zs, xdbl, wb_dt, b_dt, A_log, Dp, yv);

  gemm_bt<EPI_OUT><<<MT * 4, 256, 0, stream>>>(
      yv, 1024, wb_out, 1024, MT, nullptr, nullptr, nullptr, nullptr, x, out);
}

// Round 4
// 854.699 us; speedup vs baseline: 1.4250x; 1.0689x over previous
//
#include <hip/hip_runtime.h>

typedef unsigned short u16;
typedef unsigned int   u32;
typedef __bf16 bf16_t;
typedef bf16_t bf16x8 __attribute__((ext_vector_type(8)));
typedef float  f32x4  __attribute__((ext_vector_type(4)));

#define DEV static __device__ __forceinline__

// ---- constants ----
// B=4096, L=17, D_MODEL=512, D_INNER=1024, D_STATE=4, DT_RANK=32
// M = B*L = 69632 = 544 * 128
__constant__ int c_HOP[17] = {0,1,4,7,2,5,8,3,6,9,11,14,10,12,15,13,16};
__constant__ int c_BPE[17] = {0,1,2,0,1,2,0,1,2,0,3,4,0,3,4,3,4};
// GRAPH is HOP^-1, so out row for ssm row (b,gl) is b*17 + HOP[gl].

DEV u16 f2bf(float f){
  u32 x = __builtin_bit_cast(u32, f);
  x += 0x7fffu + ((x >> 16) & 1u);        // RNE (no NaN inputs here)
  return (u16)(x >> 16);
}
DEV float bf2f(u32 u){ return __builtin_bit_cast(float, u << 16); }
DEV float silu_f(float v){ return v / (1.f + __expf(-v)); }
DEV float softplus_f(float s){ return (s > 20.f) ? s : log1pf(__expf(s)); }

DEV void gll16(const void* g, void* l){
  __builtin_amdgcn_global_load_lds((__attribute__((address_space(1))) void*)g,
                                   (__attribute__((address_space(3))) void*)l,
                                   16, 0, 0);
}

// ---------------- weight f32 -> bf16 conversion ----------------
__global__ __launch_bounds__(256) void cvt4(
    const float* __restrict__ s0, u16* __restrict__ d0, int n0,
    const float* __restrict__ s1, u16* __restrict__ d1, int n1,
    const float* __restrict__ s2, u16* __restrict__ d2, int n2,
    const float* __restrict__ s3, u16* __restrict__ d3, int n3)
{
  int t = blockIdx.x * 256 + threadIdx.x;
  if (t < n0){ d0[t] = f2bf(s0[t]); return; }
  t -= n0; if (t < n1){ d1[t] = f2bf(s1[t]); return; }
  t -= n1; if (t < n2){ d2[t] = f2bf(s2[t]); return; }
  t -= n2; if (t < n3){ d3[t] = f2bf(s3[t]); }
}

// ---------------- gather + bpe + layernorm -> u (bf16) ----------------
__global__ __launch_bounds__(256) void ln_gather(
    const float* __restrict__ x, const float* __restrict__ bpe,
    const float* __restrict__ lnw, const float* __restrict__ lnb,
    u16* __restrict__ u)
{
  int tok = blockIdx.x;            // b*17 + l
  int b = tok / 17;
  int l = tok - b * 17;
  const float* xr = x   + ((size_t)b * 17 + c_HOP[l]) * 512;
  const float* br = bpe + (size_t)c_BPE[l] * 512;
  int tid = threadIdx.x;
  int d0 = tid * 2;
  float2 xv = *(const float2*)(xr + d0);
  float2 bv = *(const float2*)(br + d0);
  float v0 = xv.x + bv.x, v1 = xv.y + bv.y;

  __shared__ float red[8];
  float s = v0 + v1;
  #pragma unroll
  for (int o = 32; o; o >>= 1) s += __shfl_xor(s, o);
  if ((tid & 63) == 0) red[tid >> 6] = s;
  __syncthreads();
  float mu = (red[0] + red[1] + red[2] + red[3]) * (1.f / 512.f);
  float a0 = v0 - mu, a1 = v1 - mu;
  float q = a0 * a0 + a1 * a1;
  #pragma unroll
  for (int o = 32; o; o >>= 1) q += __shfl_xor(q, o);
  if ((tid & 63) == 0) red[4 + (tid >> 6)] = q;
  __syncthreads();
  float var = (red[4] + red[5] + red[6] + red[7]) * (1.f / 512.f);
  float rs = rsqrtf(var + 1e-5f);

  u16 o0 = f2bf(a0 * rs * lnw[d0]     + lnb[d0]);
  u16 o1 = f2bf(a1 * rs * lnw[d0 + 1] + lnb[d0 + 1]);
  u32 pack = (u32)o0 | ((u32)o1 << 16);
  *(u32*)(u + (size_t)tok * 512 + d0) = pack;
}

// ---------------- MFMA GEMM: C = A(MxK) * W(nW x K)^T ----------------
// 128x128 tile, BK=32, 4 waves (2x2), each wave 64x64 via 4x4 mfma 16x16x32.
// 2-phase double-buffered pipeline (T3-minimum): STAGE(next) issued BEFORE
// compute(cur); single __syncthreads per K-step (vmcnt(0) drain overlaps MFMA).
// Grid: nt fastest (A-panel L2 reuse), bijective XCD swizzle.
enum { EPI_SPLIT = 0, EPI_XDBL = 1, EPI_OUT = 2 };

template<int EPI>
__global__ __launch_bounds__(256) void gemm_bt(
    const u16* __restrict__ A, int lda,
    const u16* __restrict__ W, int K, int MT,
    u16* __restrict__ ob0, u16* __restrict__ ob1,
    const float* __restrict__ p0, const float* __restrict__ p1,
    const float* __restrict__ xres, float* __restrict__ fout)
{
  __shared__ u16 sA[2][128 * 32];
  __shared__ u16 sW[2][128 * 32];
  int nwg = gridDim.x;
  int cpx = nwg >> 3;
  int wg = (blockIdx.x & 7) * cpx + (blockIdx.x >> 3);
  int NT = nwg / MT;
  int nt = wg % NT, mt = wg / NT;
  int brow = mt * 128, bcol = nt * 128;
  int tid = threadIdx.x, lane = tid & 63, wid = tid >> 6;
  int wm = wid >> 1, wn = wid & 1;

  f32x4 acc[4][4] = {};

  int srow = tid >> 2;   // 0..63
  int sch  = tid & 3;    // physical chunk (XOR-swizzled on both sides)

  // per-thread global source pointers (advance by 32 elems per K-step)
  const u16* gA0 = A + (size_t)(brow + srow)      * lda + (sch ^ ((srow >> 1) & 3)) * 8;
  const u16* gA1 = A + (size_t)(brow + 64 + srow) * lda + (sch ^ (((64 + srow) >> 1) & 3)) * 8;
  const u16* gW0 = W + (size_t)(bcol + srow)      * K   + (sch ^ ((srow >> 1) & 3)) * 8;
  const u16* gW1 = W + (size_t)(bcol + 64 + srow) * K   + (sch ^ (((64 + srow) >> 1) & 3)) * 8;

  auto STAGE = [&](int buf, int kt) {
    gll16(gA0 + kt, (char*)sA[buf] + tid * 16);
    gll16(gA1 + kt, (char*)sA[buf] + tid * 16 + 4096);
    gll16(gW0 + kt, (char*)sW[buf] + tid * 16);
    gll16(gW1 + kt, (char*)sW[buf] + tid * 16 + 4096);
  };

  // LDS read offsets (loop-invariant)
  int aoff[4], boff[4];
  #pragma unroll
  for (int mi = 0; mi < 4; mi++) {
    int r = wm * 64 + mi * 16 + (lane & 15);
    int c = (lane >> 4) ^ ((r >> 1) & 3);
    aoff[mi] = r * 64 + c * 16;
  }
  #pragma unroll
  for (int ni = 0; ni < 4; ni++) {
    int r = wn * 64 + ni * 16 + (lane & 15);
    int c = (lane >> 4) ^ ((r >> 1) & 3);
    boff[ni] = r * 64 + c * 16;
  }

  auto COMPUTE = [&](int buf) {
    bf16x8 av[4], bv[4];
    #pragma unroll
    for (int mi = 0; mi < 4; mi++)
      av[mi] = *(const bf16x8*)((const char*)sA[buf] + aoff[mi]);
    #pragma unroll
    for (int ni = 0; ni < 4; ni++)
      bv[ni] = *(const bf16x8*)((const char*)sW[buf] + boff[ni]);
    #pragma unroll
    for (int mi = 0; mi < 4; mi++)
      #pragma unroll
      for (int ni = 0; ni < 4; ni++)
        acc[mi][ni] = __builtin_amdgcn_mfma_f32_16x16x32_bf16(
            av[mi], bv[ni], acc[mi][ni], 0, 0, 0);
  };

  int nsteps = K >> 5;               // 16 or 32 (always even here)
  STAGE(0, 0);
  __syncthreads();
  for (int s = 0; s < nsteps; s += 2) {
    if (s + 1 < nsteps) STAGE(1, (s + 1) << 5);
    COMPUTE(0);
    __syncthreads();
    if (s + 2 < nsteps) STAGE(0, (s + 2) << 5);
    COMPUTE(1);
    __syncthreads();
  }

  // epilogue: D[row=(lane>>4)*4+rr][col=lane&15] per 16x16 fragment
  int r4 = (lane >> 4) * 4;
  int cl = lane & 15;
  #pragma unroll
  for (int mi = 0; mi < 4; mi++) {
    int rowb = brow + wm * 64 + mi * 16 + r4;
    #pragma unroll
    for (int ni = 0; ni < 4; ni++) {
      int col = bcol + wn * 64 + ni * 16 + cl;
      if constexpr (EPI == EPI_SPLIT) {
        // cols [0,1024): xm = silu(v*conv_w+conv_b); [1024,2048): zs = silu(v)
        bool isx = (col < 1024);
        float cw = isx ? p0[col] : 1.f;
        float cb = isx ? p1[col] : 0.f;
        u16* dst = isx ? (ob0 + col) : (ob1 + col - 1024);
        #pragma unroll
        for (int rr = 0; rr < 4; rr++)
          dst[(size_t)(rowb + rr) * 1024] = f2bf(silu_f(acc[mi][ni][rr] * cw + cb));
      } else if constexpr (EPI == EPI_XDBL) {
        if (col < 40) {
          #pragma unroll
          for (int rr = 0; rr < 4; rr++)
            ob0[(size_t)(rowb + rr) * 40 + col] = f2bf(acc[mi][ni][rr]);
        }
      } else {  // EPI_OUT: residual add + GRAPH^-1(=HOP) scatter
        #pragma unroll
        for (int rr = 0; rr < 4; rr++) {
          int row = rowb + rr;
          u32 rw = (u32)row;
          u32 b = rw / 17u;
          int gl = (int)(rw - b * 17u);
          size_t oi = ((size_t)b * 17 + c_HOP[gl]) * 512 + col;
          fout[oi] = xres[oi] + acc[mi][ni][rr];
        }
      }
    }
  }
}

// ---------------- fused dt_proj + selective scan ----------------
// Grid: 16384 blocks = 4096 batches x 4 e-strips of 256. Thread <-> (b, e).
__global__ __launch_bounds__(256) void scan2(
    const u16* __restrict__ xm, const u16* __restrict__ zs,
    const u16* __restrict__ xdbl, const u16* __restrict__ wdt,
    const float* __restrict__ bdt, const float* __restrict__ A_log,
    const float* __restrict__ Dp, u16* __restrict__ y)
{
  __shared__ u16 xs[17 * 40];          // x_dbl[b] raw bf16 (1360 B)
  __shared__ u16 dt_s[17][264];        // softplus(dt) bf16; 528B stride

  int b = blockIdx.x >> 2;
  int er0 = (blockIdx.x & 3) * 256;
  int tid = threadIdx.x, lane = tid & 63, wid = tid >> 6;
  int l15 = lane & 15, lhi = lane >> 4;
  const size_t base = (size_t)b * 17 * 1024;

  {
    const u32* src = (const u32*)(xdbl + (size_t)b * 680);
    for (int i = tid; i < 340; i += 256) ((u32*)xs)[i] = src[i];
  }
  __syncthreads();

  // dt = softplus(x_dbl[:, :32] @ wdt^T + bdt) — M=17(pad32), K=32,
  // wave covers 64 e-columns (4 N-frags), 8 MFMA total.
  {
    bf16x8 a0 = *(const bf16x8*)(xs + l15 * 40 + lhi * 8);  // rows t=0..15
    bf16x8 a1 = *(const bf16x8*)(xs + 16 * 40 + lhi * 8);   // row t=16
    #pragma unroll
    for (int nf = 0; nf < 4; nf++) {
      int colc = wid * 64 + nf * 16 + l15;     // bijective over 0..255
      int e = er0 + colc;
      bf16x8 bv = *(const bf16x8*)(wdt + (size_t)e * 32 + lhi * 8);
      f32x4 c0 = {}, c1 = {};
      c0 = __builtin_amdgcn_mfma_f32_16x16x32_bf16(a0, bv, c0, 0, 0, 0);
      c1 = __builtin_amdgcn_mfma_f32_16x16x32_bf16(a1, bv, c1, 0, 0, 0);
      float bb = bdt[e];
      #pragma unroll
      for (int rr = 0; rr < 4; rr++) {
        int t = lhi * 4 + rr;
        if (t < 17) dt_s[t][colc] = f2bf(softplus_f(c0[rr] + bb));
      }
      if (lhi == 0) dt_s[16][colc] = f2bf(softplus_f(c1[0] + bb));
    }
  }
  __syncthreads();

  // scan: thread owns channel e = er0 + tid
  {
    int e = er0 + tid;
    float4 al = *(const float4*)(A_log + (size_t)e * 4);
    float Av0 = -__expf(al.x), Av1 = -__expf(al.y);
    float Av2 = -__expf(al.z), Av3 = -__expf(al.w);
    float Dv = Dp[e];
    const u16* xmb = xm + base + e;
    const u16* zsb = zs + base + e;
    u16* yb = y + base + e;
    float h0 = 0.f, h1 = 0.f, h2 = 0.f, h3 = 0.f;
    #pragma unroll
    for (int t = 0; t < 17; t++) {
      float dtv = bf2f(dt_s[t][tid]);
      float xv = bf2f(xmb[t * 1024]);
      float zv = bf2f(zsb[t * 1024]);
      uint4 raw = *(const uint4*)(xs + t * 40 + 32);   // B,C bf16 broadcast
      float B0 = bf2f(raw.x & 0xffffu), B1 = bf2f(raw.x >> 16);
      float B2 = bf2f(raw.y & 0xffffu), B3 = bf2f(raw.y >> 16);
      float C0 = bf2f(raw.z & 0xffffu), C1 = bf2f(raw.z >> 16);
      float C2 = bf2f(raw.w & 0xffffu), C3 = bf2f(raw.w >> 16);
      float dx = dtv * xv;
      h0 = __expf(dtv * Av0) * h0 + dx * B0;
      h1 = __expf(dtv * Av1) * h1 + dx * B1;
      h2 = __expf(dtv * Av2) * h2 + dx * B2;
      h3 = __expf(dtv * Av3) * h3 + dx * B3;
      float yv = h0 * C0 + h1 * C1 + h2 * C2 + h3 * C3;
      yb[t * 1024] = f2bf((yv + xv * Dv) * zv);
    }
  }
}

// ---------------- launch ----------------
extern "C" void kernel_launch(void* const* d_in, const int* in_sizes, int n_in,
                              void* d_out, int out_size, void* d_ws, size_t ws_size,
                              hipStream_t stream) {
  const float* x     = (const float*)d_in[0];
  const float* bpe   = (const float*)d_in[1];
  const float* lnw   = (const float*)d_in[2];
  const float* lnb   = (const float*)d_in[3];
  const float* w_in  = (const float*)d_in[4];   // (2048, 512)
  const float* convw = (const float*)d_in[5];
  const float* convb = (const float*)d_in[6];
  const float* w_xp  = (const float*)d_in[7];   // (40, 1024)
  const float* w_dt  = (const float*)d_in[8];   // (1024, 32)
  const float* b_dt  = (const float*)d_in[9];
  const float* A_log = (const float*)d_in[10];  // (1024, 4)
  const float* Dp    = (const float*)d_in[11];
  const float* w_out = (const float*)d_in[12];  // (512, 1024)
  float* out = (float*)d_out;

  // workspace layout (u16 elements) — total ~437 MB
  u16* ws = (u16*)d_ws;
  u16* wb_in  = ws;                       // 1048576
  u16* wb_out = wb_in  + 1048576;         // 524288
  u16* wb_xp  = wb_out + 524288;          // 40960
  u16* wb_dt  = wb_xp  + 40960;           // 32768
  u16* xm     = wb_dt  + 32768;           // 71303168
  u16* zs     = xm     + 71303168;        // 71303168
  u16* xdbl   = zs     + 71303168;        // 2785280
  u16* yv     = xdbl   + 2785280;         // 71303168
  u16* u      = yv;                       // 69632*512 — dead before yv written

  const int MT = 544;   // 69632 / 128

  cvt4<<<6432, 256, 0, stream>>>(w_in, wb_in, 1048576, w_out, wb_out, 524288,
                                 w_xp, wb_xp, 40960, w_dt, wb_dt, 32768);

  ln_gather<<<69632, 256, 0, stream>>>(x, bpe, lnw, lnb, u);

  gemm_bt<EPI_SPLIT><<<MT * 16, 256, 0, stream>>>(
      u, 512, wb_in, 512, MT, xm, zs, convw, convb, nullptr, nullptr);

  gemm_bt<EPI_XDBL><<<MT * 1, 256, 0, stream>>>(
      xm, 1024, wb_xp, 1024, MT, xdbl, nullptr, nullptr, nullptr, nullptr, nullptr);

  scan2<<<16384, 256, 0, stream>>>(xm, zs, xdbl, wb_dt, b_dt, A_log, Dp, yv);

  gemm_bt<EPI_OUT><<<MT * 4, 256, 0, stream>>>(
      yv, 1024, wb_out, 1024, MT, nullptr, nullptr, nullptr, nullptr, x, out);
}